// Round 2
// baseline (1104.602 us; speedup 1.0000x reference)
//
#include <hip/hip_runtime.h>

#define BATCH 16
#define CCH   512
#define LSEQ  1024
#define NH    8
#define HD    64
#define NG    32
#define CPG   16
#define EPS   1e-5f

// ---------------- GroupNorm: one block per (group, batch) -------------------
// group = 16 channels x 1024 = 16384 floats. Stats + apply in one kernel.
__global__ __launch_bounds__(256) void gn_kernel(
    const float* __restrict__ x, const float* __restrict__ nw,
    const float* __restrict__ nb, float* __restrict__ h)
{
  const int g = blockIdx.x, b = blockIdx.y;
  const size_t base = ((size_t)b * CCH + (size_t)g * CPG) * LSEQ;
  const float4* __restrict__ x4 = (const float4*)(x + base);
  float4* __restrict__ h4 = (float4*)(h + base);
  const int tid = threadIdx.x;

  float4 v[16];
  float s = 0.f, s2 = 0.f;
#pragma unroll
  for (int r = 0; r < 16; ++r) {
    v[r] = x4[tid + 256 * r];
    s  += (v[r].x + v[r].y) + (v[r].z + v[r].w);
    s2 += (v[r].x * v[r].x + v[r].y * v[r].y) + (v[r].z * v[r].z + v[r].w * v[r].w);
  }
#pragma unroll
  for (int m = 1; m < 64; m <<= 1) {
    s  += __shfl_xor(s, m);
    s2 += __shfl_xor(s2, m);
  }
  __shared__ float red0[4], red1[4];
  const int wid = tid >> 6;
  if ((tid & 63) == 0) { red0[wid] = s; red1[wid] = s2; }
  __syncthreads();
  const float ts  = (red0[0] + red0[1]) + (red0[2] + red0[3]);
  const float ts2 = (red1[0] + red1[1]) + (red1[2] + red1[3]);
  const float mean = ts * (1.f / 16384.f);
  const float var  = ts2 * (1.f / 16384.f) - mean * mean;
  const float rstd = rsqrtf(var + EPS);
#pragma unroll
  for (int r = 0; r < 16; ++r) {
    const int e = tid + 256 * r;
    const int c = g * CPG + (e >> 8);          // 256 float4 per channel
    const float sc = rstd * nw[c];
    const float sh = nb[c] - mean * sc;
    float4 o = v[r];
    o.x = o.x * sc + sh; o.y = o.y * sc + sh;
    o.z = o.z * sc + sh; o.w = o.w * sc + sh;
    h4[e] = o;
  }
}

// ---------------- fp32 GEMM: out[b] = W(MxK) @ act[b](KxN) + bias (+resid) --
// 128x128 block tile, BK=16, 256 threads, 8x8 per thread.
template<int M, bool RESID>
__global__ __launch_bounds__(256) void gemm_kernel(
    const float* __restrict__ W, const float* __restrict__ bias,
    const float* __restrict__ act, const float* __restrict__ resid,
    float* __restrict__ out)
{
  constexpr int K = CCH;    // 512
  constexpr int N = LSEQ;   // 1024
  const int b  = blockIdx.z;
  const int m0 = blockIdx.y * 128;
  const int n0 = blockIdx.x * 128;
  const float* __restrict__ Bm = act + (size_t)b * K * N;
  float* __restrict__ Cm = out + (size_t)b * M * N;

  __shared__ float As[16][132];   // [k][m], transposed on store
  __shared__ float Bs[16][132];   // [k][n]
  const int tid = threadIdx.x;
  const int tx = tid & 15, ty = tid >> 4;

  float acc[8][8] = {};

  for (int k0 = 0; k0 < K; k0 += 16) {
    __syncthreads();
#pragma unroll
    for (int r = 0; r < 2; ++r) {               // A tile: 128 rows x 16 k
      const int f = tid + 256 * r;
      const int row = f >> 2;
      const int c4 = (f & 3) << 2;
      const float4 va = *(const float4*)&W[(size_t)(m0 + row) * K + k0 + c4];
      As[c4 + 0][row] = va.x; As[c4 + 1][row] = va.y;
      As[c4 + 2][row] = va.z; As[c4 + 3][row] = va.w;
    }
#pragma unroll
    for (int r = 0; r < 2; ++r) {               // B tile: 16 k x 128 n
      const int f = tid + 256 * r;
      const int kk = f >> 5;
      const int c4 = (f & 31) << 2;
      *(float4*)&Bs[kk][c4] = *(const float4*)&Bm[(size_t)(k0 + kk) * N + n0 + c4];
    }
    __syncthreads();
#pragma unroll
    for (int kk = 0; kk < 16; ++kk) {
      const float4 a0 = *(const float4*)&As[kk][8 * ty];
      const float4 a1 = *(const float4*)&As[kk][8 * ty + 4];
      const float4 b0 = *(const float4*)&Bs[kk][8 * tx];
      const float4 b1 = *(const float4*)&Bs[kk][8 * tx + 4];
      const float av[8] = {a0.x, a0.y, a0.z, a0.w, a1.x, a1.y, a1.z, a1.w};
      const float bv[8] = {b0.x, b0.y, b0.z, b0.w, b1.x, b1.y, b1.z, b1.w};
#pragma unroll
      for (int i = 0; i < 8; ++i)
#pragma unroll
        for (int j = 0; j < 8; ++j)
          acc[i][j] = fmaf(av[i], bv[j], acc[i][j]);
    }
  }
#pragma unroll
  for (int i = 0; i < 8; ++i) {
    const int m = m0 + 8 * ty + i;
    const float bb = bias[m];
#pragma unroll
    for (int jj = 0; jj < 2; ++jj) {
      const int n = n0 + 8 * tx + 4 * jj;
      float4 o;
      o.x = acc[i][4 * jj + 0] + bb;
      o.y = acc[i][4 * jj + 1] + bb;
      o.z = acc[i][4 * jj + 2] + bb;
      o.w = acc[i][4 * jj + 3] + bb;
      if (RESID) {
        const float4 rx = *(const float4*)&resid[(size_t)b * M * N + (size_t)m * N + n];
        o.x += rx.x; o.y += rx.y; o.z += rx.z; o.w += rx.w;
      }
      *(float4*)&Cm[(size_t)m * N + n] = o;
    }
  }
}

// ---------------- flash attention: block = (64 q-rows, head, batch) ---------
// qkv layout (B, 3*C, L): Q^T/K^T/V^T are [d][l], l contiguous.
__global__ __launch_bounds__(256) void attn_kernel(
    const float* __restrict__ qkv, float* __restrict__ aout)
{
  const int it = blockIdx.x, n = blockIdx.y, b = blockIdx.z;
  const size_t bstr = (size_t)3 * CCH * LSEQ;
  const float* __restrict__ QT = qkv + b * bstr + (size_t)(n * HD) * LSEQ;
  const float* __restrict__ KT = QT + (size_t)CCH * LSEQ;
  const float* __restrict__ VT = QT + (size_t)2 * CCH * LSEQ;
  const int i0 = it * 64;

  __shared__ float qs[64][68];   // [d][i]
  __shared__ float ks[64][68];   // [d][j]
  __shared__ float vs[64][68];   // [j][d]  (transposed on store)
  __shared__ float ps[64][68];   // [j][i]  (P transposed; reused for output)

  const int tid = threadIdx.x;
  const int tx = tid & 15, ty = tid >> 4;

#pragma unroll
  for (int r = 0; r < 16; ++r) {
    const int e = tid + 256 * r;
    const int d = e >> 6, i = e & 63;
    qs[d][i] = QT[(size_t)d * LSEQ + i0 + i] * 0.125f;   // fold hd^-0.5
  }

  float m_r[4], l_r[4], o[4][4] = {};
#pragma unroll
  for (int r = 0; r < 4; ++r) { m_r[r] = -3.0e38f; l_r[r] = 0.f; }

  for (int jt = 0; jt < 16; ++jt) {
    const int j0 = jt * 64;
    __syncthreads();
#pragma unroll
    for (int r = 0; r < 16; ++r) {
      const int e = tid + 256 * r;
      const int d = e >> 6, j = e & 63;
      ks[d][j] = KT[(size_t)d * LSEQ + j0 + j];
      vs[j][d] = VT[(size_t)d * LSEQ + j0 + j];
    }
    __syncthreads();

    // S tile 64x64: rows i=4ty+r, cols j=4tx+c
    float s[4][4] = {};
#pragma unroll 16
    for (int d = 0; d < 64; ++d) {
      const float4 q4 = *(const float4*)&qs[d][4 * ty];
      const float4 k4 = *(const float4*)&ks[d][4 * tx];
      const float qa[4] = {q4.x, q4.y, q4.z, q4.w};
      const float ka[4] = {k4.x, k4.y, k4.z, k4.w};
#pragma unroll
      for (int r = 0; r < 4; ++r)
#pragma unroll
        for (int c = 0; c < 4; ++c)
          s[r][c] = fmaf(qa[r], ka[c], s[r][c]);
    }

    // online softmax; row r is owned by the 16 tx-lanes (consecutive in wave)
#pragma unroll
    for (int r = 0; r < 4; ++r) {
      float mx = fmaxf(fmaxf(s[r][0], s[r][1]), fmaxf(s[r][2], s[r][3]));
#pragma unroll
      for (int msk = 1; msk < 16; msk <<= 1) mx = fmaxf(mx, __shfl_xor(mx, msk));
      const float mnew = fmaxf(m_r[r], mx);
      const float corr = __expf(m_r[r] - mnew);
      float rs = 0.f;
#pragma unroll
      for (int c = 0; c < 4; ++c) { s[r][c] = __expf(s[r][c] - mnew); rs += s[r][c]; }
#pragma unroll
      for (int msk = 1; msk < 16; msk <<= 1) rs += __shfl_xor(rs, msk);
      l_r[r] = l_r[r] * corr + rs;
      m_r[r] = mnew;
#pragma unroll
      for (int c = 0; c < 4; ++c) o[r][c] *= corr;
#pragma unroll
      for (int c = 0; c < 4; ++c) ps[4 * tx + c][4 * ty + r] = s[r][c];
    }
    __syncthreads();

    // O[i][d] += P[i][j] * V[j][d]
#pragma unroll 16
    for (int j = 0; j < 64; ++j) {
      const float4 p4 = *(const float4*)&ps[j][4 * ty];
      const float4 v4 = *(const float4*)&vs[j][4 * tx];
      const float pa[4] = {p4.x, p4.y, p4.z, p4.w};
      const float va[4] = {v4.x, v4.y, v4.z, v4.w};
#pragma unroll
      for (int r = 0; r < 4; ++r)
#pragma unroll
        for (int c = 0; c < 4; ++c)
          o[r][c] = fmaf(pa[r], va[c], o[r][c]);
    }
  }

  // finalize + transpose through LDS for coalesced [c][l] store
  __syncthreads();
#pragma unroll
  for (int r = 0; r < 4; ++r) {
    const float inv = 1.f / l_r[r];
#pragma unroll
    for (int c = 0; c < 4; ++c) ps[4 * tx + c][4 * ty + r] = o[r][c] * inv;
  }
  __syncthreads();

  float* __restrict__ OT = aout + (size_t)b * CCH * LSEQ + (size_t)(n * HD) * LSEQ;
#pragma unroll
  for (int r = 0; r < 16; ++r) {
    const int e = tid + 256 * r;
    const int d = e >> 6, i = e & 63;
    OT[(size_t)d * LSEQ + i0 + i] = ps[d][i];
  }
}

// ---------------------------------------------------------------------------
extern "C" void kernel_launch(void* const* d_in, const int* in_sizes, int n_in,
                              void* d_out, int out_size, void* d_ws, size_t ws_size,
                              hipStream_t stream)
{
  const float* x      = (const float*)d_in[0];
  const float* norm_w = (const float*)d_in[1];
  const float* norm_b = (const float*)d_in[2];
  const float* qkv_w  = (const float*)d_in[3];
  const float* qkv_b  = (const float*)d_in[4];
  const float* proj_w = (const float*)d_in[5];
  const float* proj_b = (const float*)d_in[6];
  float* out = (float*)d_out;

  char* ws = (char*)d_ws;
  float* h   = (float*)ws;                              // 32 MiB; reused as attn out
  float* qkv = (float*)(ws + (size_t)32 * 1024 * 1024); // 96 MiB

  gn_kernel<<<dim3(NG, BATCH), 256, 0, stream>>>(x, norm_w, norm_b, h);
  gemm_kernel<3 * CCH, false><<<dim3(8, 12, BATCH), 256, 0, stream>>>(
      qkv_w, qkv_b, h, nullptr, qkv);
  attn_kernel<<<dim3(16, NH, BATCH), 256, 0, stream>>>(qkv, h);
  gemm_kernel<CCH, true><<<dim3(8, 4, BATCH), 256, 0, stream>>>(
      proj_w, proj_b, h, x, out);
}

// Round 3
// 286.148 us; speedup vs baseline: 3.8602x; 3.8602x over previous
//
#include <hip/hip_runtime.h>

#define BATCH 16
#define CCH   512
#define LSEQ  1024
#define NH    8
#define HD    64
#define NG    32
#define CPG   16
#define EPS   1e-5f

typedef __attribute__((ext_vector_type(8))) short short8;
typedef __attribute__((ext_vector_type(4))) float f32x4;
#define MFMA __builtin_amdgcn_mfma_f32_16x16x32_bf16

__device__ inline short f2bf(float f) {          // RNE, finite inputs only
  unsigned u = __float_as_uint(f);
  u += 0x7FFFu + ((u >> 16) & 1u);
  return (short)(u >> 16);
}

// ---------------- weight fp32 -> bf16 ---------------------------------------
__global__ __launch_bounds__(256) void cvt_kernel(const float* __restrict__ src,
                                                  short* __restrict__ dst) {
  const int i = blockIdx.x * 256 + threadIdx.x;          // 1 float4 each
  const float4 v = ((const float4*)src)[i];
  short vals[4] = {f2bf(v.x), f2bf(v.y), f2bf(v.z), f2bf(v.w)};
  *(uint2*)(dst + (size_t)i * 4) = *(uint2*)vals;
}

// ---------------- GroupNorm -> hT[b][l][c] bf16 -----------------------------
__global__ __launch_bounds__(256) void gn_kernel(
    const float* __restrict__ x, const float* __restrict__ nw,
    const float* __restrict__ nb, short* __restrict__ hT)
{
  const int g = blockIdx.x, b = blockIdx.y;
  const size_t base = ((size_t)b * CCH + (size_t)g * CPG) * LSEQ;
  const float4* __restrict__ x4 = (const float4*)(x + base);
  const int tid = threadIdx.x;

  __shared__ short T[16][1026];
  __shared__ float red0[4], red1[4];

  float4 v[16];
  float s = 0.f, s2 = 0.f;
#pragma unroll
  for (int r = 0; r < 16; ++r) {
    v[r] = x4[tid + 256 * r];
    s  += (v[r].x + v[r].y) + (v[r].z + v[r].w);
    s2 += (v[r].x * v[r].x + v[r].y * v[r].y) + (v[r].z * v[r].z + v[r].w * v[r].w);
  }
#pragma unroll
  for (int m = 1; m < 64; m <<= 1) { s += __shfl_xor(s, m); s2 += __shfl_xor(s2, m); }
  const int wid = tid >> 6;
  if ((tid & 63) == 0) { red0[wid] = s; red1[wid] = s2; }
  __syncthreads();
  const float ts  = (red0[0] + red0[1]) + (red0[2] + red0[3]);
  const float ts2 = (red1[0] + red1[1]) + (red1[2] + red1[3]);
  const float mean = ts * (1.f / 16384.f);
  const float var  = ts2 * (1.f / 16384.f) - mean * mean;
  const float rstd = rsqrtf(var + EPS);
#pragma unroll
  for (int r = 0; r < 16; ++r) {
    const int e = tid + 256 * r;
    const int c = e >> 8, l4 = (e & 255) * 4;
    const float sc = rstd * nw[g * CPG + c];
    const float sh = nb[g * CPG + c] - mean * sc;
    T[c][l4 + 0] = f2bf(v[r].x * sc + sh);
    T[c][l4 + 1] = f2bf(v[r].y * sc + sh);
    T[c][l4 + 2] = f2bf(v[r].z * sc + sh);
    T[c][l4 + 3] = f2bf(v[r].w * sc + sh);
  }
  __syncthreads();
  short* __restrict__ outp = hT + (size_t)b * LSEQ * CCH + g * CPG;
#pragma unroll
  for (int it = 0; it < 4; ++it) {
    const int l = tid + 256 * it;
    short vals[16];
#pragma unroll
    for (int c = 0; c < 16; ++c) vals[c] = T[c][l];
    *(short8*)(outp + (size_t)l * CCH)     = *(short8*)&vals[0];
    *(short8*)(outp + (size_t)l * CCH + 8) = *(short8*)&vals[8];
  }
}

// ---------------- QKV GEMM (bf16 MFMA) --------------------------------------
// C[o][l] = W[o][:] . hT[l][:]  (both row-major over k=c). Epilogue:
//   region 0 (o<512):   qT[b][l][c] = (C+bias)*0.125   (LDS transpose)
//   region 1 (K):       kT[b][l][c] = C+bias           (LDS transpose)
//   region 2 (V):       v [b][c][l] = C+bias
__global__ __launch_bounds__(256) void qkv_gemm(
    const short* __restrict__ Wb, const float* __restrict__ bias,
    const short* __restrict__ hT, short* __restrict__ qT,
    short* __restrict__ kT, short* __restrict__ vv)
{
  const int b = blockIdx.z, my = blockIdx.y;
  const int m0 = my * 128, n0 = blockIdx.x * 128;
  const short* __restrict__ Bsrc = hT + (size_t)b * LSEQ * CCH;

  __shared__ short smem[2 * 128 * 72];
  short (*As)[72] = (short (*)[72])smem;
  short (*Bs)[72] = (short (*)[72])(smem + 128 * 72);

  const int tid = threadIdx.x, lane = tid & 63, w = tid >> 6;
  const int wm = (w >> 1) * 64, wn = (w & 1) * 64;
  const int l15 = lane & 15, l4g = lane >> 4;
  const int srow = tid >> 3, sk8 = (tid & 7) * 8;

  const f32x4 fz = {0.f, 0.f, 0.f, 0.f};
  f32x4 acc[4][4];
#pragma unroll
  for (int i = 0; i < 4; ++i)
#pragma unroll
    for (int j = 0; j < 4; ++j) acc[i][j] = fz;

  for (int k0 = 0; k0 < CCH; k0 += 64) {
    __syncthreads();
#pragma unroll
    for (int it = 0; it < 4; ++it) {
      const int row = srow + it * 32;
      *(short8*)&As[row][sk8] = *(const short8*)(Wb + (size_t)(m0 + row) * CCH + k0 + sk8);
      *(short8*)&Bs[row][sk8] = *(const short8*)(Bsrc + (size_t)(n0 + row) * CCH + k0 + sk8);
    }
    __syncthreads();
#pragma unroll
    for (int kk = 0; kk < 2; ++kk) {
      const int ko = kk * 32 + l4g * 8;
      short8 af[4], bf[4];
#pragma unroll
      for (int i = 0; i < 4; ++i) af[i] = *(const short8*)&As[wm + i * 16 + l15][ko];
#pragma unroll
      for (int j = 0; j < 4; ++j) bf[j] = *(const short8*)&Bs[wn + j * 16 + l15][ko];
#pragma unroll
      for (int i = 0; i < 4; ++i)
#pragma unroll
        for (int j = 0; j < 4; ++j)
          acc[i][j] = MFMA(af[i], bf[j], acc[i][j], 0, 0, 0);
    }
  }

  const int region = my >> 2;                      // 0=Q 1=K 2=V
  const float scale = (region == 0) ? 0.125f : 1.0f;
  short (*CT)[136] = (short (*)[136])smem;         // 128x136 <= 2*128*72

  __syncthreads();
#pragma unroll
  for (int i = 0; i < 4; ++i)
#pragma unroll
    for (int r = 0; r < 4; ++r) {
      const int cl = wm + i * 16 + l4g * 4 + r;    // channel within 128-tile
      const float bb = bias[m0 + cl];
#pragma unroll
      for (int j = 0; j < 4; ++j) {
        const int ll = wn + j * 16 + l15;          // l within 128-tile
        const short bv = f2bf((acc[i][j][r] + bb) * scale);
        if (region == 2) CT[cl][ll] = bv; else CT[ll][cl] = bv;
      }
    }
  __syncthreads();
#pragma unroll
  for (int it = 0; it < 8; ++it) {
    const int f = tid + it * 256;
    const int rr = f >> 4, c8 = (f & 15) * 8;
    const short8 val = *(const short8*)&CT[rr][c8];
    if (region == 2) {
      *(short8*)(vv + (size_t)b * CCH * LSEQ + (size_t)((my & 3) * 128 + rr) * LSEQ + n0 + c8) = val;
    } else {
      short* __restrict__ dst = (region == 0) ? qT : kT;
      *(short8*)(dst + (size_t)b * LSEQ * CCH + (size_t)(n0 + rr) * CCH + (my & 3) * 128 + c8) = val;
    }
  }
}

// ---------------- flash attention (bf16 MFMA) -------------------------------
__global__ __launch_bounds__(256) void attn_kernel(
    const short* __restrict__ qT, const short* __restrict__ kT,
    const short* __restrict__ vv, short* __restrict__ oT)
{
  const int qt = blockIdx.x, hd = blockIdx.y, b = blockIdx.z;
  const int l0 = qt * 128, h64 = hd * 64;
  const int tid = threadIdx.x, lane = tid & 63, w = tid >> 6;
  const int l15 = lane & 15, l4g = lane >> 4;
  const int wq = w * 32;

  __shared__ short Ks[64][72];
  __shared__ short Vs[64][72];
  __shared__ short Pl[128][72];

  const short* __restrict__ qb = qT + (size_t)b * LSEQ * CCH;
  const short* __restrict__ kb = kT + (size_t)b * LSEQ * CCH;
  const short* __restrict__ vb = vv + (size_t)b * CCH * LSEQ;

  short8 qf[2][2];
#pragma unroll
  for (int mf = 0; mf < 2; ++mf)
#pragma unroll
    for (int kk = 0; kk < 2; ++kk)
      qf[mf][kk] = *(const short8*)(qb + (size_t)(l0 + wq + mf * 16 + l15) * CCH + h64 + kk * 32 + l4g * 8);

  const f32x4 fz = {0.f, 0.f, 0.f, 0.f};
  f32x4 o[2][4];
  float mr[8], lr[8];
#pragma unroll
  for (int mf = 0; mf < 2; ++mf)
#pragma unroll
    for (int df = 0; df < 4; ++df) o[mf][df] = fz;
#pragma unroll
  for (int r = 0; r < 8; ++r) { mr[r] = -1.0e30f; lr[r] = 0.f; }

  const int srow = tid >> 3, sk8 = (tid & 7) * 8;

  for (int jt = 0; jt < 16; ++jt) {
    const int j0 = jt * 64;
    __syncthreads();
#pragma unroll
    for (int it = 0; it < 2; ++it) {
      const int row = srow + it * 32;
      *(short8*)&Ks[row][sk8] = *(const short8*)(kb + (size_t)(j0 + row) * CCH + h64 + sk8);
      *(short8*)&Vs[row][sk8] = *(const short8*)(vb + (size_t)(h64 + row) * LSEQ + j0 + sk8);
    }
    __syncthreads();

    f32x4 s[2][4];
#pragma unroll
    for (int mf = 0; mf < 2; ++mf)
#pragma unroll
      for (int j = 0; j < 4; ++j) s[mf][j] = fz;
#pragma unroll
    for (int kk = 0; kk < 2; ++kk) {
      const int ko = kk * 32 + l4g * 8;
      short8 kf[4];
#pragma unroll
      for (int j = 0; j < 4; ++j) kf[j] = *(const short8*)&Ks[j * 16 + l15][ko];
#pragma unroll
      for (int mf = 0; mf < 2; ++mf)
#pragma unroll
        for (int j = 0; j < 4; ++j)
          s[mf][j] = MFMA(qf[mf][kk], kf[j], s[mf][j], 0, 0, 0);
    }

    // online softmax: lane owns rows (l4g*4+r) of each 16-row frag
#pragma unroll
    for (int mf = 0; mf < 2; ++mf)
#pragma unroll
      for (int r = 0; r < 4; ++r) {
        const int ri = mf * 4 + r;
        float mx = fmaxf(fmaxf(s[mf][0][r], s[mf][1][r]), fmaxf(s[mf][2][r], s[mf][3][r]));
#pragma unroll
        for (int msk = 1; msk < 16; msk <<= 1) mx = fmaxf(mx, __shfl_xor(mx, msk));
        const float mnew = fmaxf(mr[ri], mx);
        const float corr = __expf(mr[ri] - mnew);
        float rs = 0.f;
#pragma unroll
        for (int j = 0; j < 4; ++j) { const float p = __expf(s[mf][j][r] - mnew); s[mf][j][r] = p; rs += p; }
#pragma unroll
        for (int msk = 1; msk < 16; msk <<= 1) rs += __shfl_xor(rs, msk);
        lr[ri] = lr[ri] * corr + rs;
        mr[ri] = mnew;
#pragma unroll
        for (int j = 0; j < 4; ++j) o[mf][j][r] *= corr;
      }

    // P -> LDS (XOR-swizzled, own-wave stripe: no barrier needed)
#pragma unroll
    for (int mf = 0; mf < 2; ++mf)
#pragma unroll
      for (int r = 0; r < 4; ++r) {
        const int i = wq + mf * 16 + l4g * 4 + r;
        const int sw = ((i >> 2) & 3) << 4;
#pragma unroll
        for (int j = 0; j < 4; ++j) Pl[i][(j * 16 + l15) ^ sw] = f2bf(s[mf][j][r]);
      }

    // O += P.V^T-rows
#pragma unroll
    for (int kk = 0; kk < 2; ++kk) {
      const int ko = kk * 32 + l4g * 8;
      short8 pf[2], vf[4];
#pragma unroll
      for (int mf = 0; mf < 2; ++mf) {
        const int i = wq + mf * 16 + l15;
        pf[mf] = *(const short8*)&Pl[i][ko ^ (((i >> 2) & 3) << 4)];
      }
#pragma unroll
      for (int df = 0; df < 4; ++df) vf[df] = *(const short8*)&Vs[df * 16 + l15][ko];
#pragma unroll
      for (int mf = 0; mf < 2; ++mf)
#pragma unroll
        for (int df = 0; df < 4; ++df)
          o[mf][df] = MFMA(pf[mf], vf[df], o[mf][df], 0, 0, 0);
    }
  }

  short* __restrict__ ob = oT + (size_t)b * LSEQ * CCH;
#pragma unroll
  for (int mf = 0; mf < 2; ++mf)
#pragma unroll
    for (int r = 0; r < 4; ++r) {
      const float inv = 1.f / lr[mf * 4 + r];
      const int gl = l0 + wq + mf * 16 + l4g * 4 + r;
#pragma unroll
      for (int df = 0; df < 4; ++df)
        ob[(size_t)gl * CCH + h64 + df * 16 + l15] = f2bf(o[mf][df][r] * inv);
    }
}

// ---------------- proj GEMM + bias + residual -> fp32 out -------------------
__global__ __launch_bounds__(256) void proj_gemm(
    const short* __restrict__ Wb, const float* __restrict__ bias,
    const short* __restrict__ oT, const float* __restrict__ x,
    float* __restrict__ out)
{
  const int b = blockIdx.z;
  const int m0 = blockIdx.y * 128, n0 = blockIdx.x * 128;
  const short* __restrict__ Bsrc = oT + (size_t)b * LSEQ * CCH;

  __shared__ short As[128][72];
  __shared__ short Bs[128][72];

  const int tid = threadIdx.x, lane = tid & 63, w = tid >> 6;
  const int wm = (w >> 1) * 64, wn = (w & 1) * 64;
  const int l15 = lane & 15, l4g = lane >> 4;
  const int srow = tid >> 3, sk8 = (tid & 7) * 8;

  const f32x4 fz = {0.f, 0.f, 0.f, 0.f};
  f32x4 acc[4][4];
#pragma unroll
  for (int i = 0; i < 4; ++i)
#pragma unroll
    for (int j = 0; j < 4; ++j) acc[i][j] = fz;

  for (int k0 = 0; k0 < CCH; k0 += 64) {
    __syncthreads();
#pragma unroll
    for (int it = 0; it < 4; ++it) {
      const int row = srow + it * 32;
      *(short8*)&As[row][sk8] = *(const short8*)(Wb + (size_t)(m0 + row) * CCH + k0 + sk8);
      *(short8*)&Bs[row][sk8] = *(const short8*)(Bsrc + (size_t)(n0 + row) * CCH + k0 + sk8);
    }
    __syncthreads();
#pragma unroll
    for (int kk = 0; kk < 2; ++kk) {
      const int ko = kk * 32 + l4g * 8;
      short8 af[4], bf[4];
#pragma unroll
      for (int i = 0; i < 4; ++i) af[i] = *(const short8*)&As[wm + i * 16 + l15][ko];
#pragma unroll
      for (int j = 0; j < 4; ++j) bf[j] = *(const short8*)&Bs[wn + j * 16 + l15][ko];
#pragma unroll
      for (int i = 0; i < 4; ++i)
#pragma unroll
        for (int j = 0; j < 4; ++j)
          acc[i][j] = MFMA(af[i], bf[j], acc[i][j], 0, 0, 0);
    }
  }

  const size_t obase = (size_t)b * CCH * LSEQ;
#pragma unroll
  for (int i = 0; i < 4; ++i)
#pragma unroll
    for (int r = 0; r < 4; ++r) {
      const int gm = m0 + wm + i * 16 + l4g * 4 + r;
      const float bb = bias[gm];
#pragma unroll
      for (int j = 0; j < 4; ++j) {
        const int gl = n0 + wn + j * 16 + l15;
        const size_t idx = obase + (size_t)gm * LSEQ + gl;
        out[idx] = acc[i][j][r] + bb + x[idx];
      }
    }
}

// ---------------------------------------------------------------------------
extern "C" void kernel_launch(void* const* d_in, const int* in_sizes, int n_in,
                              void* d_out, int out_size, void* d_ws, size_t ws_size,
                              hipStream_t stream)
{
  const float* x      = (const float*)d_in[0];
  const float* norm_w = (const float*)d_in[1];
  const float* norm_b = (const float*)d_in[2];
  const float* qkv_w  = (const float*)d_in[3];
  const float* qkv_b  = (const float*)d_in[4];
  const float* proj_w = (const float*)d_in[5];
  const float* proj_b = (const float*)d_in[6];
  float* out = (float*)d_out;

  char* ws = (char*)d_ws;
  short* wq16 = (short*)ws;                                   // 1536*512*2 = 1.5M
  short* wp16 = (short*)(ws + 1572864);                       // 512*512*2  = 0.5M
  short* hT   = (short*)(ws + 2097152);                       // 16M
  short* qT   = (short*)(ws + 2097152 + 16777216);            // 16M
  short* kT   = (short*)(ws + 2097152 + 2 * 16777216);        // 16M
  short* vv   = (short*)(ws + 2097152 + 3 * 16777216);        // 16M
  short* oT   = (short*)(ws + 2097152 + 4 * 16777216);        // 16M

  cvt_kernel<<<768, 256, 0, stream>>>(qkv_w, wq16);
  cvt_kernel<<<256, 256, 0, stream>>>(proj_w, wp16);
  gn_kernel<<<dim3(NG, BATCH), 256, 0, stream>>>(x, norm_w, norm_b, hT);
  qkv_gemm<<<dim3(8, 12, BATCH), 256, 0, stream>>>(wq16, qkv_b, hT, qT, kT, vv);
  attn_kernel<<<dim3(8, NH, BATCH), 256, 0, stream>>>(qT, kT, vv, oT);
  proj_gemm<<<dim3(8, 4, BATCH), 256, 0, stream>>>(wp16, proj_b, oT, x, out);
}

// Round 4
// 260.860 us; speedup vs baseline: 4.2345x; 1.0969x over previous
//
#include <hip/hip_runtime.h>

#define BATCH 16
#define CCH   512
#define LSEQ  1024
#define NH    8
#define HD    64
#define NG    32
#define CPG   16
#define EPS   1e-5f

typedef __attribute__((ext_vector_type(8))) short short8;
typedef __attribute__((ext_vector_type(4))) float f32x4;
#define MFMA __builtin_amdgcn_mfma_f32_16x16x32_bf16

__device__ inline short f2bf(float f) {          // RNE, finite inputs only
  unsigned u = __float_as_uint(f);
  u += 0x7FFFu + ((u >> 16) & 1u);
  return (short)(u >> 16);
}

// ---------------- weight fp32 -> bf16 ---------------------------------------
__global__ __launch_bounds__(256) void cvt_kernel(const float* __restrict__ src,
                                                  short* __restrict__ dst) {
  const int i = blockIdx.x * 256 + threadIdx.x;          // 1 float4 each
  const float4 v = ((const float4*)src)[i];
  short vals[4] = {f2bf(v.x), f2bf(v.y), f2bf(v.z), f2bf(v.w)};
  *(uint2*)(dst + (size_t)i * 4) = *(uint2*)vals;
}

// ---------------- GroupNorm -> hT[b][l][c] bf16 -----------------------------
__global__ __launch_bounds__(256) void gn_kernel(
    const float* __restrict__ x, const float* __restrict__ nw,
    const float* __restrict__ nb, short* __restrict__ hT)
{
  const int g = blockIdx.x, b = blockIdx.y;
  const size_t base = ((size_t)b * CCH + (size_t)g * CPG) * LSEQ;
  const float4* __restrict__ x4 = (const float4*)(x + base);
  const int tid = threadIdx.x;

  __shared__ short T[16][1026];
  __shared__ float red0[4], red1[4];

  float4 v[16];
  float s = 0.f, s2 = 0.f;
#pragma unroll
  for (int r = 0; r < 16; ++r) {
    v[r] = x4[tid + 256 * r];
    s  += (v[r].x + v[r].y) + (v[r].z + v[r].w);
    s2 += (v[r].x * v[r].x + v[r].y * v[r].y) + (v[r].z * v[r].z + v[r].w * v[r].w);
  }
#pragma unroll
  for (int m = 1; m < 64; m <<= 1) { s += __shfl_xor(s, m); s2 += __shfl_xor(s2, m); }
  const int wid = tid >> 6;
  if ((tid & 63) == 0) { red0[wid] = s; red1[wid] = s2; }
  __syncthreads();
  const float ts  = (red0[0] + red0[1]) + (red0[2] + red0[3]);
  const float ts2 = (red1[0] + red1[1]) + (red1[2] + red1[3]);
  const float mean = ts * (1.f / 16384.f);
  const float var  = ts2 * (1.f / 16384.f) - mean * mean;
  const float rstd = rsqrtf(var + EPS);
#pragma unroll
  for (int r = 0; r < 16; ++r) {
    const int e = tid + 256 * r;
    const int c = e >> 8, l4 = (e & 255) * 4;
    const float sc = rstd * nw[g * CPG + c];
    const float sh = nb[g * CPG + c] - mean * sc;
    T[c][l4 + 0] = f2bf(v[r].x * sc + sh);
    T[c][l4 + 1] = f2bf(v[r].y * sc + sh);
    T[c][l4 + 2] = f2bf(v[r].z * sc + sh);
    T[c][l4 + 3] = f2bf(v[r].w * sc + sh);
  }
  __syncthreads();
  short* __restrict__ outp = hT + (size_t)b * LSEQ * CCH + g * CPG;
#pragma unroll
  for (int it = 0; it < 4; ++it) {
    const int l = tid + 256 * it;
    short vals[16];
#pragma unroll
    for (int c = 0; c < 16; ++c) vals[c] = T[c][l];
    *(short8*)(outp + (size_t)l * CCH)     = *(short8*)&vals[0];
    *(short8*)(outp + (size_t)l * CCH + 8) = *(short8*)&vals[8];
  }
}

// ---------------- QKV GEMM (bf16 MFMA) --------------------------------------
__global__ __launch_bounds__(256) void qkv_gemm(
    const short* __restrict__ Wb, const float* __restrict__ bias,
    const short* __restrict__ hT, short* __restrict__ qT,
    short* __restrict__ kT, short* __restrict__ vv)
{
  const int b = blockIdx.z, my = blockIdx.y;
  const int m0 = my * 128, n0 = blockIdx.x * 128;
  const short* __restrict__ Bsrc = hT + (size_t)b * LSEQ * CCH;

  __shared__ short smem[2 * 128 * 72];
  short (*As)[72] = (short (*)[72])smem;
  short (*Bs)[72] = (short (*)[72])(smem + 128 * 72);

  const int tid = threadIdx.x, lane = tid & 63, w = tid >> 6;
  const int wm = (w >> 1) * 64, wn = (w & 1) * 64;
  const int l15 = lane & 15, l4g = lane >> 4;
  const int srow = tid >> 3, sk8 = (tid & 7) * 8;

  const f32x4 fz = {0.f, 0.f, 0.f, 0.f};
  f32x4 acc[4][4];
#pragma unroll
  for (int i = 0; i < 4; ++i)
#pragma unroll
    for (int j = 0; j < 4; ++j) acc[i][j] = fz;

  for (int k0 = 0; k0 < CCH; k0 += 64) {
    __syncthreads();
#pragma unroll
    for (int it = 0; it < 4; ++it) {
      const int row = srow + it * 32;
      *(short8*)&As[row][sk8] = *(const short8*)(Wb + (size_t)(m0 + row) * CCH + k0 + sk8);
      *(short8*)&Bs[row][sk8] = *(const short8*)(Bsrc + (size_t)(n0 + row) * CCH + k0 + sk8);
    }
    __syncthreads();
#pragma unroll
    for (int kk = 0; kk < 2; ++kk) {
      const int ko = kk * 32 + l4g * 8;
      short8 af[4], bf[4];
#pragma unroll
      for (int i = 0; i < 4; ++i) af[i] = *(const short8*)&As[wm + i * 16 + l15][ko];
#pragma unroll
      for (int j = 0; j < 4; ++j) bf[j] = *(const short8*)&Bs[wn + j * 16 + l15][ko];
#pragma unroll
      for (int i = 0; i < 4; ++i)
#pragma unroll
        for (int j = 0; j < 4; ++j)
          acc[i][j] = MFMA(af[i], bf[j], acc[i][j], 0, 0, 0);
    }
  }

  const int region = my >> 2;                      // 0=Q 1=K 2=V
  const float scale = (region == 0) ? 0.125f : 1.0f;
  short (*CT)[136] = (short (*)[136])smem;         // 128x136 <= 2*128*72

  __syncthreads();
#pragma unroll
  for (int i = 0; i < 4; ++i)
#pragma unroll
    for (int r = 0; r < 4; ++r) {
      const int cl = wm + i * 16 + l4g * 4 + r;    // channel within 128-tile
      const float bb = bias[m0 + cl];
#pragma unroll
      for (int j = 0; j < 4; ++j) {
        const int ll = wn + j * 16 + l15;          // l within 128-tile
        const short bv = f2bf((acc[i][j][r] + bb) * scale);
        if (region == 2) CT[cl][ll] = bv; else CT[ll][cl] = bv;
      }
    }
  __syncthreads();
#pragma unroll
  for (int it = 0; it < 8; ++it) {
    const int f = tid + it * 256;
    const int rr = f >> 4, c8 = (f & 15) * 8;
    const short8 val = *(const short8*)&CT[rr][c8];
    if (region == 2) {
      *(short8*)(vv + (size_t)b * CCH * LSEQ + (size_t)((my & 3) * 128 + rr) * LSEQ + n0 + c8) = val;
    } else {
      short* __restrict__ dst = (region == 0) ? qT : kT;
      *(short8*)(dst + (size_t)b * LSEQ * CCH + (size_t)(n0 + rr) * CCH + (my & 3) * 128 + c8) = val;
    }
  }
}

// ---------------- flash attention, swapped-QK^T (bf16 MFMA) -----------------
// Wave owns 16 q-rows. mfma(K,Q) => lane holds P[kv=j*16+l4g*4+r][q=l15]:
// row-softmax is 15 in-reg max + 2 shfl. P repacked to u32 words in an
// own-wave LDS stripe; one ds_read_b128 rebuilds the x32 A-frag for PV.
__global__ __launch_bounds__(256) void attn_kernel(
    const short* __restrict__ qT, const short* __restrict__ kT,
    const short* __restrict__ vv, short* __restrict__ oT)
{
  const int qt = blockIdx.x, hh = blockIdx.y, b = blockIdx.z;
  const int l0 = qt * 64, h64 = hh * 64;
  const int tid = threadIdx.x, lane = tid & 63, w = tid >> 6;
  const int l15 = lane & 15, l4g = lane >> 4;
  const int wq = w * 16;

  __shared__ short Ks[64][72];
  __shared__ short Vs[64][72];
  __shared__ unsigned Pw[4][16][36];   // [wave][q][u32 word], pad 36 for banks

  const short* __restrict__ qb = qT + (size_t)b * LSEQ * CCH;
  const short* __restrict__ kb = kT + (size_t)b * LSEQ * CCH;
  const short* __restrict__ vb = vv + (size_t)b * CCH * LSEQ;

  // Q as B-operand: B[n=q=l15][k=c], 8 contiguous c per lane
  short8 qf[2];
#pragma unroll
  for (int kk = 0; kk < 2; ++kk)
    qf[kk] = *(const short8*)(qb + (size_t)(l0 + wq + l15) * CCH + h64 + kk * 32 + l4g * 8);

  const f32x4 fz = {0.f, 0.f, 0.f, 0.f};
  f32x4 o[4];                          // O[q=l4g*4+r][d=df*16+l15]
#pragma unroll
  for (int df = 0; df < 4; ++df) o[df] = fz;
  float mr = -1.0e30f, lr = 0.f;       // state for q = l15

  const int srow = tid >> 3, sk8 = (tid & 7) * 8;

  for (int jt = 0; jt < 16; ++jt) {
    const int j0 = jt * 64;
    __syncthreads();
#pragma unroll
    for (int it = 0; it < 2; ++it) {
      const int row = srow + it * 32;
      *(short8*)&Ks[row][sk8] = *(const short8*)(kb + (size_t)(j0 + row) * CCH + h64 + sk8);
      *(short8*)&Vs[row][sk8] = *(const short8*)(vb + (size_t)(h64 + row) * LSEQ + j0 + sk8);
    }
    __syncthreads();

    // S' = K.Q^T : s[j] rows kv=j*16+l4g*4+r, col q=l15
    f32x4 s[4];
#pragma unroll
    for (int j = 0; j < 4; ++j) s[j] = fz;
#pragma unroll
    for (int kk = 0; kk < 2; ++kk) {
      const int ko = kk * 32 + l4g * 8;
      short8 kf[4];
#pragma unroll
      for (int j = 0; j < 4; ++j) kf[j] = *(const short8*)&Ks[j * 16 + l15][ko];
#pragma unroll
      for (int j = 0; j < 4; ++j) s[j] = MFMA(kf[j], qf[kk], s[j], 0, 0, 0);
    }

    // online softmax for q=l15 (64 kv values: 16 in-reg x 4 lane-groups)
    float mx = s[0][0];
#pragma unroll
    for (int j = 0; j < 4; ++j)
#pragma unroll
      for (int r = 0; r < 4; ++r) mx = fmaxf(mx, s[j][r]);
    mx = fmaxf(mx, __shfl_xor(mx, 16));
    mx = fmaxf(mx, __shfl_xor(mx, 32));
    const float mnew = fmaxf(mr, mx);
    const float corr = __expf(mr - mnew);
    mr = mnew;

    float rs = 0.f;
    unsigned pk[4][2];
#pragma unroll
    for (int j = 0; j < 4; ++j) {
      float p0 = __expf(s[j][0] - mnew), p1 = __expf(s[j][1] - mnew);
      float p2 = __expf(s[j][2] - mnew), p3 = __expf(s[j][3] - mnew);
      rs += (p0 + p1) + (p2 + p3);
      pk[j][0] = (unsigned)(unsigned short)f2bf(p0) | ((unsigned)(unsigned short)f2bf(p1) << 16);
      pk[j][1] = (unsigned)(unsigned short)f2bf(p2) | ((unsigned)(unsigned short)f2bf(p3) << 16);
    }
    rs += __shfl_xor(rs, 16);
    rs += __shfl_xor(rs, 32);
    lr = lr * corr + rs;

    // P -> own-wave LDS stripe (word W = kv/2; lane owns W%8 in {2*l4g,2*l4g+1})
#pragma unroll
    for (int j = 0; j < 4; ++j)
      *(uint2*)&Pw[w][l15][j * 8 + l4g * 2] = make_uint2(pk[j][0], pk[j][1]);

    // rescale O: lane's O rows are q = l4g*4+r
    float cb[4];
#pragma unroll
    for (int r = 0; r < 4; ++r) cb[r] = __shfl(corr, l4g * 4 + r);
#pragma unroll
    for (int df = 0; df < 4; ++df)
#pragma unroll
      for (int r = 0; r < 4; ++r) o[df][r] *= cb[r];

    // O += P.V  (A-frag from Pw: row q=l15, kv = kk*32 + l4g*8 .. +8)
#pragma unroll
    for (int kk = 0; kk < 2; ++kk) {
      const short8 pf = *(const short8*)&Pw[w][l15][kk * 16 + l4g * 4];
      const int ko = kk * 32 + l4g * 8;
#pragma unroll
      for (int df = 0; df < 4; ++df) {
        const short8 vf = *(const short8*)&Vs[df * 16 + l15][ko];
        o[df] = MFMA(pf, vf, o[df], 0, 0, 0);
      }
    }
  }

  // finalize: lane's O rows are q = l4g*4+r; l lives at lane q
  float lb[4];
#pragma unroll
  for (int r = 0; r < 4; ++r) lb[r] = 1.f / __shfl(lr, l4g * 4 + r);
  short* __restrict__ ob = oT + (size_t)b * LSEQ * CCH;
#pragma unroll
  for (int df = 0; df < 4; ++df)
#pragma unroll
    for (int r = 0; r < 4; ++r)
      ob[(size_t)(l0 + wq + l4g * 4 + r) * CCH + h64 + df * 16 + l15] = f2bf(o[df][r] * lb[r]);
}

// ---------------- proj GEMM + bias + residual -> fp32 out -------------------
__global__ __launch_bounds__(256) void proj_gemm(
    const short* __restrict__ Wb, const float* __restrict__ bias,
    const short* __restrict__ oT, const float* __restrict__ x,
    float* __restrict__ out)
{
  const int b = blockIdx.z;
  const int m0 = blockIdx.y * 128, n0 = blockIdx.x * 128;
  const short* __restrict__ Bsrc = oT + (size_t)b * LSEQ * CCH;

  __shared__ short As[128][72];
  __shared__ short Bs[128][72];

  const int tid = threadIdx.x, lane = tid & 63, w = tid >> 6;
  const int wm = (w >> 1) * 64, wn = (w & 1) * 64;
  const int l15 = lane & 15, l4g = lane >> 4;
  const int srow = tid >> 3, sk8 = (tid & 7) * 8;

  const f32x4 fz = {0.f, 0.f, 0.f, 0.f};
  f32x4 acc[4][4];
#pragma unroll
  for (int i = 0; i < 4; ++i)
#pragma unroll
    for (int j = 0; j < 4; ++j) acc[i][j] = fz;

  for (int k0 = 0; k0 < CCH; k0 += 64) {
    __syncthreads();
#pragma unroll
    for (int it = 0; it < 4; ++it) {
      const int row = srow + it * 32;
      *(short8*)&As[row][sk8] = *(const short8*)(Wb + (size_t)(m0 + row) * CCH + k0 + sk8);
      *(short8*)&Bs[row][sk8] = *(const short8*)(Bsrc + (size_t)(n0 + row) * CCH + k0 + sk8);
    }
    __syncthreads();
#pragma unroll
    for (int kk = 0; kk < 2; ++kk) {
      const int ko = kk * 32 + l4g * 8;
      short8 af[4], bf[4];
#pragma unroll
      for (int i = 0; i < 4; ++i) af[i] = *(const short8*)&As[wm + i * 16 + l15][ko];
#pragma unroll
      for (int j = 0; j < 4; ++j) bf[j] = *(const short8*)&Bs[wn + j * 16 + l15][ko];
#pragma unroll
      for (int i = 0; i < 4; ++i)
#pragma unroll
        for (int j = 0; j < 4; ++j)
          acc[i][j] = MFMA(af[i], bf[j], acc[i][j], 0, 0, 0);
    }
  }

  const size_t obase = (size_t)b * CCH * LSEQ;
#pragma unroll
  for (int i = 0; i < 4; ++i)
#pragma unroll
    for (int r = 0; r < 4; ++r) {
      const int gm = m0 + wm + i * 16 + l4g * 4 + r;
      const float bb = bias[gm];
#pragma unroll
      for (int j = 0; j < 4; ++j) {
        const int gl = n0 + wn + j * 16 + l15;
        const size_t idx = obase + (size_t)gm * LSEQ + gl;
        out[idx] = acc[i][j][r] + bb + x[idx];
      }
    }
}

// ---------------------------------------------------------------------------
extern "C" void kernel_launch(void* const* d_in, const int* in_sizes, int n_in,
                              void* d_out, int out_size, void* d_ws, size_t ws_size,
                              hipStream_t stream)
{
  const float* x      = (const float*)d_in[0];
  const float* norm_w = (const float*)d_in[1];
  const float* norm_b = (const float*)d_in[2];
  const float* qkv_w  = (const float*)d_in[3];
  const float* qkv_b  = (const float*)d_in[4];
  const float* proj_w = (const float*)d_in[5];
  const float* proj_b = (const float*)d_in[6];
  float* out = (float*)d_out;

  char* ws = (char*)d_ws;
  short* wq16 = (short*)ws;                                   // 1536*512*2 = 1.5M
  short* wp16 = (short*)(ws + 1572864);                       // 512*512*2  = 0.5M
  short* hT   = (short*)(ws + 2097152);                       // 16M
  short* qT   = (short*)(ws + 2097152 + 16777216);            // 16M
  short* kT   = (short*)(ws + 2097152 + 2 * 16777216);        // 16M
  short* vv   = (short*)(ws + 2097152 + 3 * 16777216);        // 16M
  short* oT   = (short*)(ws + 2097152 + 4 * 16777216);        // 16M

  cvt_kernel<<<768, 256, 0, stream>>>(qkv_w, wq16);
  cvt_kernel<<<256, 256, 0, stream>>>(proj_w, wp16);
  gn_kernel<<<dim3(NG, BATCH), 256, 0, stream>>>(x, norm_w, norm_b, hT);
  qkv_gemm<<<dim3(8, 12, BATCH), 256, 0, stream>>>(wq16, qkv_b, hT, qT, kT, vv);
  attn_kernel<<<dim3(16, NH, BATCH), 256, 0, stream>>>(qT, kT, vv, oT);
  proj_gemm<<<dim3(8, 4, BATCH), 256, 0, stream>>>(wp16, proj_b, oT, x, out);
}

// Round 7
// 243.065 us; speedup vs baseline: 4.5445x; 1.0732x over previous
//
#include <hip/hip_runtime.h>
#include <hip/hip_bf16.h>

#define BATCH 16
#define CCH   512
#define LSEQ  1024
#define NH    8
#define HD    64
#define NG    32
#define CPG   16
#define EPS   1e-5f

typedef __attribute__((ext_vector_type(8))) short short8;
typedef __attribute__((ext_vector_type(4))) float f32x4;
#define MFMA __builtin_amdgcn_mfma_f32_16x16x32_bf16

__device__ inline short f2bf(float f) {          // RNE, finite inputs only
  unsigned u = __float_as_uint(f);
  u += 0x7FFFu + ((u >> 16) & 1u);
  return (short)(u >> 16);
}

// async global->LDS, 16B per lane; LDS dest is wave-uniform base + lane*16
__device__ inline void gl2lds16(const short* g, short* l) {
  __builtin_amdgcn_global_load_lds(
      (const __attribute__((address_space(1))) unsigned*)g,
      (__attribute__((address_space(3))) unsigned*)l, 16, 0, 0);
}
#define VMCNT0() asm volatile("s_waitcnt vmcnt(0)" ::: "memory")

// ---------------- weight fp32 -> bf16 ---------------------------------------
__global__ __launch_bounds__(256) void cvt_kernel(const float* __restrict__ src,
                                                  short* __restrict__ dst) {
  const int i = blockIdx.x * 256 + threadIdx.x;          // 1 float4 each
  const float4 v = ((const float4*)src)[i];
  short vals[4] = {f2bf(v.x), f2bf(v.y), f2bf(v.z), f2bf(v.w)};
  *(uint2*)(dst + (size_t)i * 4) = *(uint2*)vals;
}

// ---------------- GroupNorm -> hT[b][l][c] bf16 -----------------------------
__global__ __launch_bounds__(256) void gn_kernel(
    const float* __restrict__ x, const float* __restrict__ nw,
    const float* __restrict__ nb, short* __restrict__ hT)
{
  const int g = blockIdx.x, b = blockIdx.y;
  const size_t base = ((size_t)b * CCH + (size_t)g * CPG) * LSEQ;
  const float4* __restrict__ x4 = (const float4*)(x + base);
  const int tid = threadIdx.x;

  __shared__ short T[16][1026];
  __shared__ float red0[4], red1[4];

  float4 v[16];
  float s = 0.f, s2 = 0.f;
#pragma unroll
  for (int r = 0; r < 16; ++r) {
    v[r] = x4[tid + 256 * r];
    s  += (v[r].x + v[r].y) + (v[r].z + v[r].w);
    s2 += (v[r].x * v[r].x + v[r].y * v[r].y) + (v[r].z * v[r].z + v[r].w * v[r].w);
  }
#pragma unroll
  for (int m = 1; m < 64; m <<= 1) { s += __shfl_xor(s, m); s2 += __shfl_xor(s2, m); }
  const int wid = tid >> 6;
  if ((tid & 63) == 0) { red0[wid] = s; red1[wid] = s2; }
  __syncthreads();
  const float ts  = (red0[0] + red0[1]) + (red0[2] + red0[3]);
  const float ts2 = (red1[0] + red1[1]) + (red1[2] + red1[3]);
  const float mean = ts * (1.f / 16384.f);
  const float var  = ts2 * (1.f / 16384.f) - mean * mean;
  const float rstd = rsqrtf(var + EPS);
#pragma unroll
  for (int r = 0; r < 16; ++r) {
    const int e = tid + 256 * r;
    const int c = e >> 8, l4 = (e & 255) * 4;
    const float sc = rstd * nw[g * CPG + c];
    const float sh = nb[g * CPG + c] - mean * sc;
    T[c][l4 + 0] = f2bf(v[r].x * sc + sh);
    T[c][l4 + 1] = f2bf(v[r].y * sc + sh);
    T[c][l4 + 2] = f2bf(v[r].z * sc + sh);
    T[c][l4 + 3] = f2bf(v[r].w * sc + sh);
  }
  __syncthreads();
  short* __restrict__ outp = hT + (size_t)b * LSEQ * CCH + g * CPG;
#pragma unroll
  for (int it = 0; it < 4; ++it) {
    const int l = tid + 256 * it;
    short vals[16];
#pragma unroll
    for (int c = 0; c < 16; ++c) vals[c] = T[c][l];
    *(short8*)(outp + (size_t)l * CCH)     = *(short8*)&vals[0];
    *(short8*)(outp + (size_t)l * CCH + 8) = *(short8*)&vals[8];
  }
}

// ---------------- QKV GEMM (bf16 MFMA, gl_lds 2-phase dbuf) -----------------
// LDS rows: 64 shorts (128B), XOR-swizzled: slot s within row r holds global
// k-chunk (s ^ (r&7)); gl_lds writes linearly, source pre-swizzled.
__global__ __launch_bounds__(256) void qkv_gemm(
    const short* __restrict__ Wb, const float* __restrict__ bias,
    const short* __restrict__ hT, short* __restrict__ qT,
    short* __restrict__ kT, short* __restrict__ vv)
{
  const int b = blockIdx.z, my = blockIdx.y;
  const int m0 = my * 128, n0 = blockIdx.x * 128;
  const short* __restrict__ Bsrc = hT + (size_t)b * LSEQ * CCH;

  __shared__ short smem[32768];            // [A:2x128x64][B:2x128x64] = 64KB
  const int tid = threadIdx.x, lane = tid & 63, w = tid >> 6;
  const int wm = (w >> 1) * 64, wn = (w & 1) * 64;
  const int l15 = lane & 15, l4g = lane >> 4;
  const int sr = lane >> 3, c8 = ((lane & 7) ^ (lane >> 3)) * 8;
  const int swz = (l15 & 7) << 4;

  const f32x4 fz = {0.f, 0.f, 0.f, 0.f};
  f32x4 acc[4][4];
#pragma unroll
  for (int i = 0; i < 4; ++i)
#pragma unroll
    for (int j = 0; j < 4; ++j) acc[i][j] = fz;

#define QSTAGE(ks, bb)                                                        \
  {                                                                           \
    const int k0_ = (ks) * 64;                                                \
    _Pragma("unroll")                                                         \
    for (int i_ = 0; i_ < 4; ++i_) {                                          \
      const int rb_ = w * 32 + i_ * 8;                                        \
      gl2lds16(Wb   + (size_t)(m0 + rb_ + sr) * CCH + k0_ + c8,               \
               &smem[(bb) * 8192 + rb_ * 64]);                                \
      gl2lds16(Bsrc + (size_t)(n0 + rb_ + sr) * CCH + k0_ + c8,               \
               &smem[16384 + (bb) * 8192 + rb_ * 64]);                        \
    }                                                                         \
  }

  QSTAGE(0, 0);
  VMCNT0();
  __syncthreads();

  for (int ks = 0; ks < 8; ++ks) {
    const int bb = ks & 1;
    if (ks < 7) QSTAGE(ks + 1, bb ^ 1);
#pragma unroll
    for (int kk = 0; kk < 2; ++kk) {
      const int ko = (kk * 64 + l4g * 16) ^ swz;
      short8 af[4], bf[4];
#pragma unroll
      for (int i = 0; i < 4; ++i)
        af[i] = *(const short8*)((const char*)&smem[bb * 8192 + (wm + i * 16 + l15) * 64] + ko);
#pragma unroll
      for (int j = 0; j < 4; ++j)
        bf[j] = *(const short8*)((const char*)&smem[16384 + bb * 8192 + (wn + j * 16 + l15) * 64] + ko);
#pragma unroll
      for (int i = 0; i < 4; ++i)
#pragma unroll
        for (int j = 0; j < 4; ++j)
          acc[i][j] = MFMA(af[i], bf[j], acc[i][j], 0, 0, 0);
    }
    VMCNT0();
    __syncthreads();
  }

  const int region = my >> 2;                      // 0=Q 1=K 2=V
  const float scale = (region == 0) ? 0.125f : 1.0f;
  short (*CT)[136] = (short (*)[136])smem;         // 128x136 = 17408 < 32768

#pragma unroll
  for (int i = 0; i < 4; ++i)
#pragma unroll
    for (int r = 0; r < 4; ++r) {
      const int cl = wm + i * 16 + l4g * 4 + r;    // channel within 128-tile
      const float bb = bias[m0 + cl];
#pragma unroll
      for (int j = 0; j < 4; ++j) {
        const int ll = wn + j * 16 + l15;          // l within 128-tile
        const short bv = f2bf((acc[i][j][r] + bb) * scale);
        if (region == 2) CT[cl][ll] = bv; else CT[ll][cl] = bv;
      }
    }
  __syncthreads();
#pragma unroll
  for (int it = 0; it < 8; ++it) {
    const int f = tid + it * 256;
    const int rr = f >> 4, cc8 = (f & 15) * 8;
    const short8 val = *(const short8*)&CT[rr][cc8];
    if (region == 2) {
      *(short8*)(vv + (size_t)b * CCH * LSEQ + (size_t)((my & 3) * 128 + rr) * LSEQ + n0 + cc8) = val;
    } else {
      short* __restrict__ dst = (region == 0) ? qT : kT;
      *(short8*)(dst + (size_t)b * LSEQ * CCH + (size_t)(n0 + rr) * CCH + (my & 3) * 128 + cc8) = val;
    }
  }
}

// ---------------- flash attention, swapped-QK^T + gl_lds dbuf ---------------
__global__ __launch_bounds__(256) void attn_kernel(
    const short* __restrict__ qT, const short* __restrict__ kT,
    const short* __restrict__ vv, short* __restrict__ oT)
{
  const int qt = blockIdx.x, hh = blockIdx.y, b = blockIdx.z;
  const int l0 = qt * 64, h64 = hh * 64;
  const int tid = threadIdx.x, lane = tid & 63, w = tid >> 6;
  const int l15 = lane & 15, l4g = lane >> 4;
  const int wq = w * 16;

  __shared__ short Ks[2][64][64];
  __shared__ short Vs[2][64][64];
  __shared__ unsigned Pw[4][16][36];   // [wave][q][u32 word]

  const short* __restrict__ qb = qT + (size_t)b * LSEQ * CCH;
  const short* __restrict__ kb = kT + (size_t)b * LSEQ * CCH;
  const short* __restrict__ vb = vv + (size_t)b * CCH * LSEQ;

  // Q as B-operand: B[n=q=l15][k=c], 8 contiguous c per lane
  short8 qf[2];
#pragma unroll
  for (int kk = 0; kk < 2; ++kk)
    qf[kk] = *(const short8*)(qb + (size_t)(l0 + wq + l15) * CCH + h64 + kk * 32 + l4g * 8);

  const f32x4 fz = {0.f, 0.f, 0.f, 0.f};
  f32x4 o[4];                          // O[q=l4g*4+r][d=df*16+l15]
#pragma unroll
  for (int df = 0; df < 4; ++df) o[df] = fz;
  float mr = -1.0e30f, lr = 0.f;       // state for q = l15

  const int sr = lane >> 3, c8 = ((lane & 7) ^ (lane >> 3)) * 8;
  const int swz = (l15 & 7) << 4;

#define ASTAGE(jt_, bb)                                                       \
  {                                                                           \
    const int j0_ = (jt_) * 64;                                               \
    _Pragma("unroll")                                                         \
    for (int i_ = 0; i_ < 2; ++i_) {                                          \
      const int rb_ = w * 16 + i_ * 8;                                        \
      gl2lds16(kb + (size_t)(j0_ + rb_ + sr) * CCH + h64 + c8,                \
               &Ks[bb][rb_][0]);                                              \
      gl2lds16(vb + (size_t)(h64 + rb_ + sr) * LSEQ + j0_ + c8,               \
               &Vs[bb][rb_][0]);                                              \
    }                                                                         \
  }

  ASTAGE(0, 0);
  VMCNT0();
  __syncthreads();

  for (int jt = 0; jt < 16; ++jt) {
    const int bb = jt & 1;
    if (jt < 15) ASTAGE(jt + 1, bb ^ 1);

    // S' = K.Q^T : s[j] rows kv=j*16+l4g*4+r, col q=l15
    f32x4 s[4];
#pragma unroll
    for (int j = 0; j < 4; ++j) s[j] = fz;
#pragma unroll
    for (int kk = 0; kk < 2; ++kk) {
      const int ko = (kk * 64 + l4g * 16) ^ swz;
      short8 kf[4];
#pragma unroll
      for (int j = 0; j < 4; ++j)
        kf[j] = *(const short8*)((const char*)&Ks[bb][j * 16 + l15][0] + ko);
#pragma unroll
      for (int j = 0; j < 4; ++j) s[j] = MFMA(kf[j], qf[kk], s[j], 0, 0, 0);
    }

    // online softmax for q=l15 (64 kv values: 16 in-reg x 4 lane-groups)
    float mx = s[0][0];
#pragma unroll
    for (int j = 0; j < 4; ++j)
#pragma unroll
      for (int r = 0; r < 4; ++r) mx = fmaxf(mx, s[j][r]);
    mx = fmaxf(mx, __shfl_xor(mx, 16));
    mx = fmaxf(mx, __shfl_xor(mx, 32));
    const float mnew = fmaxf(mr, mx);
    const float corr = __expf(mr - mnew);
    mr = mnew;

    float rs = 0.f;
    unsigned pk[4][2];
#pragma unroll
    for (int j = 0; j < 4; ++j) {
      float p0 = __expf(s[j][0] - mnew), p1 = __expf(s[j][1] - mnew);
      float p2 = __expf(s[j][2] - mnew), p3 = __expf(s[j][3] - mnew);
      rs += (p0 + p1) + (p2 + p3);
      __hip_bfloat162 w0 = __float22bfloat162_rn(make_float2(p0, p1));
      __hip_bfloat162 w1 = __float22bfloat162_rn(make_float2(p2, p3));
      pk[j][0] = *(unsigned*)&w0;
      pk[j][1] = *(unsigned*)&w1;
    }
    rs += __shfl_xor(rs, 16);
    rs += __shfl_xor(rs, 32);
    lr = lr * corr + rs;

    // P -> own-wave LDS stripe
#pragma unroll
    for (int j = 0; j < 4; ++j)
      *(uint2*)&Pw[w][l15][j * 8 + l4g * 2] = make_uint2(pk[j][0], pk[j][1]);

    // rescale O: lane's O rows are q = l4g*4+r
    float cb[4];
#pragma unroll
    for (int r = 0; r < 4; ++r) cb[r] = __shfl(corr, l4g * 4 + r);
#pragma unroll
    for (int df = 0; df < 4; ++df)
#pragma unroll
      for (int r = 0; r < 4; ++r) o[df][r] *= cb[r];

    // O += P.V  (A-frag from Pw: row q=l15, kv = kk*32 + l4g*8 .. +8)
#pragma unroll
    for (int kk = 0; kk < 2; ++kk) {
      const short8 pf = *(const short8*)&Pw[w][l15][kk * 16 + l4g * 4];
      const int ko = (kk * 64 + l4g * 16) ^ swz;
#pragma unroll
      for (int df = 0; df < 4; ++df) {
        const short8 vf = *(const short8*)((const char*)&Vs[bb][df * 16 + l15][0] + ko);
        o[df] = MFMA(pf, vf, o[df], 0, 0, 0);
      }
    }
    VMCNT0();
    __syncthreads();
  }

  // finalize: lane's O rows are q = l4g*4+r
  float lb[4];
#pragma unroll
  for (int r = 0; r < 4; ++r) lb[r] = 1.f / __shfl(lr, l4g * 4 + r);
  short* __restrict__ ob = oT + (size_t)b * LSEQ * CCH;
#pragma unroll
  for (int df = 0; df < 4; ++df)
#pragma unroll
    for (int r = 0; r < 4; ++r)
      ob[(size_t)(l0 + wq + l4g * 4 + r) * CCH + h64 + df * 16 + l15] = f2bf(o[df][r] * lb[r]);
}

// ---------------- proj GEMM + bias + residual -> fp32 out -------------------
__global__ __launch_bounds__(256) void proj_gemm(
    const short* __restrict__ Wb, const float* __restrict__ bias,
    const short* __restrict__ oT, const float* __restrict__ x,
    float* __restrict__ out)
{
  const int b = blockIdx.z;
  const int m0 = blockIdx.y * 128, n0 = blockIdx.x * 128;
  const short* __restrict__ Bsrc = oT + (size_t)b * LSEQ * CCH;

  __shared__ short smem[32768];
  const int tid = threadIdx.x, lane = tid & 63, w = tid >> 6;
  const int wm = (w >> 1) * 64, wn = (w & 1) * 64;
  const int l15 = lane & 15, l4g = lane >> 4;
  const int sr = lane >> 3, c8 = ((lane & 7) ^ (lane >> 3)) * 8;
  const int swz = (l15 & 7) << 4;

  const f32x4 fz = {0.f, 0.f, 0.f, 0.f};
  f32x4 acc[4][4];
#pragma unroll
  for (int i = 0; i < 4; ++i)
#pragma unroll
    for (int j = 0; j < 4; ++j) acc[i][j] = fz;

#define PSTAGE(ks, bb)                                                        \
  {                                                                           \
    const int k0_ = (ks) * 64;                                                \
    _Pragma("unroll")                                                         \
    for (int i_ = 0; i_ < 4; ++i_) {                                          \
      const int rb_ = w * 32 + i_ * 8;                                        \
      gl2lds16(Wb   + (size_t)(m0 + rb_ + sr) * CCH + k0_ + c8,               \
               &smem[(bb) * 8192 + rb_ * 64]);                                \
      gl2lds16(Bsrc + (size_t)(n0 + rb_ + sr) * CCH + k0_ + c8,               \
               &smem[16384 + (bb) * 8192 + rb_ * 64]);                        \
    }                                                                         \
  }

  PSTAGE(0, 0);
  VMCNT0();
  __syncthreads();

  for (int ks = 0; ks < 8; ++ks) {
    const int bb = ks & 1;
    if (ks < 7) PSTAGE(ks + 1, bb ^ 1);
#pragma unroll
    for (int kk = 0; kk < 2; ++kk) {
      const int ko = (kk * 64 + l4g * 16) ^ swz;
      short8 af[4], bf[4];
#pragma unroll
      for (int i = 0; i < 4; ++i)
        af[i] = *(const short8*)((const char*)&smem[bb * 8192 + (wm + i * 16 + l15) * 64] + ko);
#pragma unroll
      for (int j = 0; j < 4; ++j)
        bf[j] = *(const short8*)((const char*)&smem[16384 + bb * 8192 + (wn + j * 16 + l15) * 64] + ko);
#pragma unroll
      for (int i = 0; i < 4; ++i)
#pragma unroll
        for (int j = 0; j < 4; ++j)
          acc[i][j] = MFMA(af[i], bf[j], acc[i][j], 0, 0, 0);
    }
    VMCNT0();
    __syncthreads();
  }

  const size_t obase = (size_t)b * CCH * LSEQ;
#pragma unroll
  for (int i = 0; i < 4; ++i)
#pragma unroll
    for (int r = 0; r < 4; ++r) {
      const int gm = m0 + wm + i * 16 + l4g * 4 + r;
      const float bb = bias[gm];
#pragma unroll
      for (int j = 0; j < 4; ++j) {
        const int gl = n0 + wn + j * 16 + l15;
        const size_t idx = obase + (size_t)gm * LSEQ + gl;
        out[idx] = acc[i][j][r] + bb + x[idx];
      }
    }
}

// ---------------------------------------------------------------------------
extern "C" void kernel_launch(void* const* d_in, const int* in_sizes, int n_in,
                              void* d_out, int out_size, void* d_ws, size_t ws_size,
                              hipStream_t stream)
{
  const float* x      = (const float*)d_in[0];
  const float* norm_w = (const float*)d_in[1];
  const float* norm_b = (const float*)d_in[2];
  const float* qkv_w  = (const float*)d_in[3];
  const float* qkv_b  = (const float*)d_in[4];
  const float* proj_w = (const float*)d_in[5];
  const float* proj_b = (const float*)d_in[6];
  float* out = (float*)d_out;

  char* ws = (char*)d_ws;
  short* wq16 = (short*)ws;                                   // 1536*512*2 = 1.5M
  short* wp16 = (short*)(ws + 1572864);                       // 512*512*2  = 0.5M
  short* hT   = (short*)(ws + 2097152);                       // 16M
  short* qT   = (short*)(ws + 2097152 + 16777216);            // 16M
  short* kT   = (short*)(ws + 2097152 + 2 * 16777216);        // 16M
  short* vv   = (short*)(ws + 2097152 + 3 * 16777216);        // 16M
  short* oT   = (short*)(ws + 2097152 + 4 * 16777216);        // 16M

  cvt_kernel<<<768, 256, 0, stream>>>(qkv_w, wq16);
  cvt_kernel<<<256, 256, 0, stream>>>(proj_w, wp16);
  gn_kernel<<<dim3(NG, BATCH), 256, 0, stream>>>(x, norm_w, norm_b, hT);
  qkv_gemm<<<dim3(8, 12, BATCH), 256, 0, stream>>>(wq16, qkv_b, hT, qT, kT, vv);
  attn_kernel<<<dim3(16, NH, BATCH), 256, 0, stream>>>(qT, kT, vv, oT);
  proj_gemm<<<dim3(8, 4, BATCH), 256, 0, stream>>>(wp16, proj_b, oT, x, out);
}